// Round 2
// baseline (878.816 us; speedup 1.0000x reference)
//
#include <hip/hip_runtime.h>
#include <math.h>

#define TT 512
#define BB 16
#define NN 512
#define HH 8
#define DD 64
#define RR 8192      // BB*NN
#define LIF_CH 32

__device__ __forceinline__ double wave_sum_d(double v){
  #pragma unroll
  for (int off = 32; off > 0; off >>= 1) v += __shfl_xor(v, off, 64);
  return v;
}

// ---------------- LayerNorm over feature dim: one wave per (t,b) row ----------------
__global__ __launch_bounds__(256) void ln_kernel(const float* __restrict__ x,
                                                 const float* __restrict__ lng,
                                                 const float* __restrict__ lnb,
                                                 float* __restrict__ out){
  int row  = (blockIdx.x * 256 + threadIdx.x) >> 6;
  int lane = threadIdx.x & 63;
  const float* src = x + (size_t)row * NN;
  int n0 = lane * 4;
  float4 v0 = *(const float4*)(src + n0);
  float4 v1 = *(const float4*)(src + 256 + n0);
  double e[8] = {v0.x, v0.y, v0.z, v0.w, v1.x, v1.y, v1.z, v1.w};
  double s = 0.0;
  #pragma unroll
  for (int i = 0; i < 8; ++i) s += e[i];
  s = wave_sum_d(s);
  double mean = s * (1.0/512.0);
  double ss = 0.0;
  #pragma unroll
  for (int i = 0; i < 8; ++i){ double d = e[i] - mean; ss += d * d; }
  ss = wave_sum_d(ss);
  double inv = 1.0 / sqrt(ss * (1.0/512.0) + 1e-5);
  float4 g0 = *(const float4*)(lng + n0);
  float4 g1 = *(const float4*)(lng + 256 + n0);
  float4 b0 = *(const float4*)(lnb + n0);
  float4 b1 = *(const float4*)(lnb + 256 + n0);
  double gg[8] = {g0.x, g0.y, g0.z, g0.w, g1.x, g1.y, g1.z, g1.w};
  double bb[8] = {b0.x, b0.y, b0.z, b0.w, b1.x, b1.y, b1.z, b1.w};
  float o[8];
  #pragma unroll
  for (int i = 0; i < 8; ++i)
    o[i] = (float)((e[i] - mean) * inv * gg[i] + bb[i]);
  float* dst = out + (size_t)row * NN;
  *(float4*)(dst + n0)       = make_float4(o[0], o[1], o[2], o[3]);
  *(float4*)(dst + 256 + n0) = make_float4(o[4], o[5], o[6], o[7]);
}

// ---------------- plain multi-step LIF over (512, 8192) flat view ----------------
// v = v*0.5 + x ; s = (v >= 1) ; hard reset v=0 on spike   (exact IEEE, matches ref bitwise)
__global__ __launch_bounds__(64) void lif_kernel(const float* __restrict__ in,
                                                 float* __restrict__ out){
  int r = blockIdx.x * 64 + threadIdx.x;
  float v = 0.0f;
  for (int t0 = 0; t0 < TT; t0 += LIF_CH){
    float xv[LIF_CH];
    #pragma unroll
    for (int i = 0; i < LIF_CH; ++i) xv[i] = in[(t0 + i) * RR + r];
    #pragma unroll
    for (int i = 0; i < LIF_CH; ++i){
      v = v * 0.5f + xv[i];
      float s = (v >= 1.0f) ? 1.0f : 0.0f;
      out[(t0 + i) * RR + r] = s;
      v = (v >= 1.0f) ? 0.0f : v;
    }
  }
}

// ---------------- eval-BatchNorm (per feature n) + LIF ----------------
__global__ __launch_bounds__(64) void lif_bn_kernel(const float* __restrict__ in,
                                                    float* __restrict__ out,
                                                    const float* __restrict__ bnp){
  int r = blockIdx.x * 64 + threadIdx.x;
  int n = r & (NN - 1);
  double g  = bnp[n];
  double be = bnp[NN + n];
  double m  = bnp[2*NN + n];
  double va = bnp[3*NN + n];
  double sc = g / sqrt(va + 1e-5);
  float v = 0.0f;
  for (int t0 = 0; t0 < TT; t0 += LIF_CH){
    float xv[LIF_CH];
    #pragma unroll
    for (int i = 0; i < LIF_CH; ++i) xv[i] = in[(t0 + i) * RR + r];
    #pragma unroll
    for (int i = 0; i < LIF_CH; ++i){
      float y = (float)(((double)xv[i] - m) * sc + be);
      v = v * 0.5f + y;
      float s = (v >= 1.0f) ? 1.0f : 0.0f;
      out[(t0 + i) * RR + r] = s;
      v = (v >= 1.0f) ? 0.0f : v;
    }
  }
}

// ---------------- rotary: in (T,B,N) -> out (B,H,T,D) contiguous; double trig ----------------
__global__ __launch_bounds__(256) void rotary_kernel(const float* __restrict__ in,
                                                     float* __restrict__ out){
  int pid = blockIdx.x * 256 + threadIdx.x;       // 2^21 pairs
  int p  = pid & 31;                              // pair index d/2
  int t  = (pid >> 5) & (TT - 1);
  int bh = pid >> 14;
  int b  = bh >> 3, h = bh & 7;
  const float2 xv = *(const float2*)(in + ((size_t)t * BB + b) * NN + h * DD + p * 2);
  double inv = pow(10000.0, -(double)p / 32.0);
  double f = (double)t * inv;
  double sn, cs;
  sincos(f, &sn, &cs);
  float2 o;
  o.x = (float)((double)xv.x * cs - (double)xv.y * sn);
  o.y = (float)((double)xv.y * cs + (double)xv.x * sn);
  *(float2*)(out + ((size_t)bh * TT + t) * DD + p * 2) = o;
}

// ---------------- GEMM: C(8192,512) = A(8192,512) @ W(512,512)^T, fp64 accumulate ----------------
__global__ __launch_bounds__(256) void gemm_kernel(const float* __restrict__ A,
                                                   const float* __restrict__ W,
                                                   float* __restrict__ C){
  __shared__ float As[32][68];   // [k][row], padded
  __shared__ float Ws[32][68];   // [k][m]
  int tid = threadIdx.x;
  int tx = tid & 15, ty = tid >> 4;
  int r0 = blockIdx.x << 6;
  int m0 = blockIdx.y << 6;
  int lk = (tid & 7) << 2;
  int lr = tid >> 3;
  double acc[4][4] = {};
  for (int kk = 0; kk < 512; kk += 32){
    float4 a0 = *(const float4*)(A + (size_t)(r0 + lr) * 512 + kk + lk);
    float4 a1 = *(const float4*)(A + (size_t)(r0 + lr + 32) * 512 + kk + lk);
    float4 w0 = *(const float4*)(W + (size_t)(m0 + lr) * 512 + kk + lk);
    float4 w1 = *(const float4*)(W + (size_t)(m0 + lr + 32) * 512 + kk + lk);
    __syncthreads();
    As[lk+0][lr] = a0.x; As[lk+1][lr] = a0.y; As[lk+2][lr] = a0.z; As[lk+3][lr] = a0.w;
    As[lk+0][lr+32] = a1.x; As[lk+1][lr+32] = a1.y; As[lk+2][lr+32] = a1.z; As[lk+3][lr+32] = a1.w;
    Ws[lk+0][lr] = w0.x; Ws[lk+1][lr] = w0.y; Ws[lk+2][lr] = w0.z; Ws[lk+3][lr] = w0.w;
    Ws[lk+0][lr+32] = w1.x; Ws[lk+1][lr+32] = w1.y; Ws[lk+2][lr+32] = w1.z; Ws[lk+3][lr+32] = w1.w;
    __syncthreads();
    #pragma unroll
    for (int k = 0; k < 32; ++k){
      double av[4], wv[4];
      #pragma unroll
      for (int i = 0; i < 4; ++i) av[i] = (double)As[k][(ty << 2) + i];
      #pragma unroll
      for (int j = 0; j < 4; ++j) wv[j] = (double)Ws[k][(tx << 2) + j];
      #pragma unroll
      for (int i = 0; i < 4; ++i)
        #pragma unroll
        for (int j = 0; j < 4; ++j) acc[i][j] += av[i] * wv[j];
    }
  }
  #pragma unroll
  for (int i = 0; i < 4; ++i){
    float4 o = make_float4((float)acc[i][0], (float)acc[i][1],
                           (float)acc[i][2], (float)acc[i][3]);
    *(float4*)(C + (size_t)(r0 + (ty << 2) + i) * 512 + m0 + (tx << 2)) = o;
  }
}

// ---------------- attention: exact in fp32 (spike*spike integers, scale 1/8) ----------------
__global__ __launch_bounds__(256) void attn_kernel(const float* __restrict__ q,
                                                   const float* __restrict__ k,
                                                   const float* __restrict__ v1,
                                                   const int* __restrict__ mask,
                                                   float* __restrict__ y){
  __shared__ float QT[64][68];   // Q^T  [d][t]
  __shared__ float KP[64][68];   // K^T  [d][s], later P [t][s]
  __shared__ float Vs[64][68];   // V    [s][d]
  int tid = threadIdx.x;
  int tx = tid & 15, ty = tid >> 4;
  int srow = tid >> 4;
  int scol = (tid & 15) << 2;
  int bh = blockIdx.y;
  int b = bh >> 3, h = bh & 7;
  int t0 = blockIdx.x << 6;
  #pragma unroll
  for (int p = 0; p < 4; ++p){
    int row = srow + (p << 4);
    float4 qq = *(const float4*)(q + ((size_t)bh * TT + t0 + row) * DD + scol);
    QT[scol+0][row] = qq.x; QT[scol+1][row] = qq.y; QT[scol+2][row] = qq.z; QT[scol+3][row] = qq.w;
  }
  float acc[4][4] = {};
  for (int s0 = 0; s0 < TT; s0 += 64){
    __syncthreads();
    #pragma unroll
    for (int p = 0; p < 4; ++p){
      int row = srow + (p << 4);
      float mm = (mask[b * TT + s0 + row] != 0) ? 1.0f : 0.0f;
      float4 kk = *(const float4*)(k + ((size_t)bh * TT + s0 + row) * DD + scol);
      KP[scol+0][row] = kk.x * mm; KP[scol+1][row] = kk.y * mm;
      KP[scol+2][row] = kk.z * mm; KP[scol+3][row] = kk.w * mm;
      float4 vv = *(const float4*)(v1 + ((size_t)(s0 + row) * BB + b) * NN + h * DD + scol);
      *(float4*)&Vs[row][scol] = vv;
    }
    __syncthreads();
    float pacc[4][4] = {};
    #pragma unroll 16
    for (int d = 0; d < 64; ++d){
      float qv[4], kv[4];
      #pragma unroll
      for (int i = 0; i < 4; ++i) qv[i] = QT[d][(ty << 2) + i];
      #pragma unroll
      for (int j = 0; j < 4; ++j) kv[j] = KP[d][(tx << 2) + j];
      #pragma unroll
      for (int i = 0; i < 4; ++i)
        #pragma unroll
        for (int j = 0; j < 4; ++j) pacc[i][j] += qv[i] * kv[j];
    }
    __syncthreads();
    #pragma unroll
    for (int i = 0; i < 4; ++i){
      float4 o = make_float4(pacc[i][0], pacc[i][1], pacc[i][2], pacc[i][3]);
      *(float4*)&KP[(ty << 2) + i][tx << 2] = o;
    }
    __syncthreads();
    #pragma unroll 16
    for (int s = 0; s < 64; ++s){
      float pv[4], vv[4];
      #pragma unroll
      for (int i = 0; i < 4; ++i) pv[i] = KP[(ty << 2) + i][s];
      #pragma unroll
      for (int j = 0; j < 4; ++j) vv[j] = Vs[s][(tx << 2) + j];
      #pragma unroll
      for (int i = 0; i < 4; ++i)
        #pragma unroll
        for (int j = 0; j < 4; ++j) acc[i][j] += pv[i] * vv[j];
    }
  }
  #pragma unroll
  for (int i = 0; i < 4; ++i){
    float4 o = make_float4(acc[i][0]*0.125f, acc[i][1]*0.125f,
                           acc[i][2]*0.125f, acc[i][3]*0.125f);
    *(float4*)(y + ((size_t)bh * TT + t0 + (ty << 2) + i) * DD + (tx << 2)) = o;
  }
}

// ---------------- attn LIF: reads (B,H,T,D), scans true t, writes (T,B,N) ----------------
__global__ __launch_bounds__(64) void lif_attn_kernel(const float* __restrict__ in,
                                                      float* __restrict__ out){
  int r = blockIdx.x * 64 + threadIdx.x;   // (bh,d)
  int bh = r >> 6, d = r & 63;
  int b = bh >> 3, h = bh & 7;
  const float* src = in + (size_t)bh * TT * DD + d;
  float* dst = out + b * NN + h * DD + d;
  float v = 0.0f;
  for (int t0 = 0; t0 < TT; t0 += LIF_CH){
    float xv[LIF_CH];
    #pragma unroll
    for (int i = 0; i < LIF_CH; ++i) xv[i] = src[(t0 + i) * DD];
    #pragma unroll
    for (int i = 0; i < LIF_CH; ++i){
      v = v * 0.5f + xv[i];
      float s = (v >= 1.0f) ? 1.0f : 0.0f;
      dst[(t0 + i) * RR] = s;
      v = (v >= 1.0f) ? 0.0f : v;
    }
  }
}

extern "C" void kernel_launch(void* const* d_in, const int* in_sizes, int n_in,
                              void* d_out, int out_size, void* d_ws, size_t ws_size,
                              hipStream_t stream){
  (void)in_sizes; (void)n_in; (void)out_size; (void)ws_size;
  const float* x    = (const float*)d_in[0];
  const int*   mask = (const int*)d_in[1];
  const float* lng  = (const float*)d_in[2];
  const float* lnb  = (const float*)d_in[3];
  const float* wq   = (const float*)d_in[4];
  const float* qbn  = (const float*)d_in[5];
  const float* wk   = (const float*)d_in[6];
  const float* kbn  = (const float*)d_in[7];
  const float* wv   = (const float*)d_in[8];
  const float* vbn  = (const float*)d_in[9];
  const float* wp   = (const float*)d_in[10];
  const float* pbn  = (const float*)d_in[11];
  float* out = (float*)d_out;

  const size_t SZ = (size_t)TT * BB * NN;   // 4M floats
  float* XS = (float*)d_ws;      // head-LIF spikes
  float* C  = XS + SZ;           // generic scratch
  float* Q  = C + SZ;            // q spikes (B,H,T,D) flat
  float* K  = Q + SZ;            // k spikes
  float* V  = K + SZ;            // v spikes (T,B,N)
  float* Dp = out;               // d_out doubles as scratch

  ln_kernel<<<2048, 256, 0, stream>>>(x, lng, lnb, C);
  lif_kernel<<<128, 64, 0, stream>>>(C, XS);

  gemm_kernel<<<dim3(128, 8), 256, 0, stream>>>(XS, wq, C);
  lif_bn_kernel<<<128, 64, 0, stream>>>(C, Dp, qbn);
  rotary_kernel<<<8192, 256, 0, stream>>>(Dp, C);
  lif_kernel<<<128, 64, 0, stream>>>(C, Q);      // raw-reshape LIF == flat (512,8192) scan

  gemm_kernel<<<dim3(128, 8), 256, 0, stream>>>(XS, wk, C);
  lif_bn_kernel<<<128, 64, 0, stream>>>(C, Dp, kbn);
  rotary_kernel<<<8192, 256, 0, stream>>>(Dp, C);
  lif_kernel<<<128, 64, 0, stream>>>(C, K);

  gemm_kernel<<<dim3(128, 8), 256, 0, stream>>>(XS, wv, C);
  lif_bn_kernel<<<128, 64, 0, stream>>>(C, V, vbn);

  attn_kernel<<<dim3(8, 128), 256, 0, stream>>>(Q, K, V, mask, C);
  lif_attn_kernel<<<128, 64, 0, stream>>>(C, Dp);

  gemm_kernel<<<dim3(128, 8), 256, 0, stream>>>(Dp, wp, C);
  lif_bn_kernel<<<128, 64, 0, stream>>>(C, out, pbn);
}

// Round 6
// 347.052 us; speedup vs baseline: 2.5322x; 2.5322x over previous
//
#include <hip/hip_runtime.h>
#include <math.h>

#define TT 512
#define BB 16
#define NN 512
#define HH 8
#define DD 64
#define RR 8192      // BB*NN
#define LIF_CH 32

typedef int v4i __attribute__((ext_vector_type(4)));

__device__ __forceinline__ double wave_sum_d(double v){
  #pragma unroll
  for (int off = 32; off > 0; off >>= 1) v += __shfl_xor(v, off, 64);
  return v;
}

// ---------------- LayerNorm over feature dim (fp64 math, fp32 out) ----------------
__global__ __launch_bounds__(256) void ln_kernel(const float* __restrict__ x,
                                                 const float* __restrict__ lng,
                                                 const float* __restrict__ lnb,
                                                 float* __restrict__ out){
  int row  = (blockIdx.x * 256 + threadIdx.x) >> 6;
  int lane = threadIdx.x & 63;
  const float* src = x + (size_t)row * NN;
  int n0 = lane * 4;
  float4 v0 = *(const float4*)(src + n0);
  float4 v1 = *(const float4*)(src + 256 + n0);
  double e[8] = {v0.x, v0.y, v0.z, v0.w, v1.x, v1.y, v1.z, v1.w};
  double s = 0.0;
  #pragma unroll
  for (int i = 0; i < 8; ++i) s += e[i];
  s = wave_sum_d(s);
  double mean = s * (1.0/512.0);
  double ss = 0.0;
  #pragma unroll
  for (int i = 0; i < 8; ++i){ double d = e[i] - mean; ss += d * d; }
  ss = wave_sum_d(ss);
  double inv = 1.0 / sqrt(ss * (1.0/512.0) + 1e-5);
  float4 g0 = *(const float4*)(lng + n0);
  float4 g1 = *(const float4*)(lng + 256 + n0);
  float4 b0 = *(const float4*)(lnb + n0);
  float4 b1 = *(const float4*)(lnb + 256 + n0);
  double gg[8] = {g0.x, g0.y, g0.z, g0.w, g1.x, g1.y, g1.z, g1.w};
  double bb[8] = {b0.x, b0.y, b0.z, b0.w, b1.x, b1.y, b1.z, b1.w};
  float o[8];
  #pragma unroll
  for (int i = 0; i < 8; ++i)
    o[i] = (float)((e[i] - mean) * inv * gg[i] + bb[i]);
  float* dst = out + (size_t)row * NN;
  *(float4*)(dst + n0)       = make_float4(o[0], o[1], o[2], o[3]);
  *(float4*)(dst + 256 + n0) = make_float4(o[4], o[5], o[6], o[7]);
}

// ---------------- weight slicing: W fp32 -> 5 signed-i8 planes, scale 2^-39 ----------------
__global__ __launch_bounds__(256) void slice_kernel(const float* __restrict__ w0,
                                                    const float* __restrict__ w1,
                                                    const float* __restrict__ w2,
                                                    const float* __restrict__ w3,
                                                    signed char* __restrict__ out){
  int id = blockIdx.x * 256 + threadIdx.x;      // 4*262144
  int wi = id >> 18, e = id & 262143;
  const float* w = wi==0 ? w0 : wi==1 ? w1 : wi==2 ? w2 : w3;
  double q = (double)w[e] * 0x1p39;
  long long Qv = (long long)rint(q);
  signed char* dst = out + ((size_t)(wi*5) << 18) + e;
  #pragma unroll
  for (int j = 0; j < 4; ++j){
    signed char bch = (signed char)(Qv & 255);
    dst[(size_t)j << 18] = bch;
    Qv = (Qv - bch) >> 8;
  }
  dst[(size_t)4 << 18] = (signed char)Qv;
}

// ---------------- rotary table: fp64 cos/sin for (t, p) ----------------
__global__ __launch_bounds__(256) void rope_table(double* __restrict__ tab){
  int id = blockIdx.x * 256 + threadIdx.x;      // 16384
  int t = id >> 5, p = id & 31;
  double inv = pow(10000.0, -(double)p / 32.0);
  double f = (double)t * inv;
  double sn, cs; sincos(f, &sn, &cs);
  tab[id*2] = cs; tab[id*2+1] = sn;
}

// ---------------- i8 slice-GEMM: C(8192, ldc) = A(8192,512 spikes) @ Wslices^T ----------------
// exact fixed-point: result = (sum_j 256^j * (A@Bj)) * 2^-39, combined in fp64
__global__ __launch_bounds__(256) void gemm_i8(const unsigned char* __restrict__ A,
                                               const signed char* __restrict__ SL,
                                               float* __restrict__ C, int ldc){
  __shared__ signed char Al[64][80];
  __shared__ signed char Bl[5][64][80];
  int tid = threadIdx.x, l = tid & 63, wv = tid >> 6;
  int r0 = blockIdx.x << 6;
  int m0 = blockIdx.y << 6;
  int mat = m0 >> 9, mm0 = m0 & 511;
  const signed char* Bbase = SL + ((size_t)(mat*5) << 18) + (size_t)mm0 * 512;
  v4i zero = {0,0,0,0};
  v4i acc[4][5];
  #pragma unroll
  for (int rf = 0; rf < 4; ++rf)
    #pragma unroll
    for (int j = 0; j < 5; ++j) acc[rf][j] = zero;
  int row = tid >> 2, ch = tid & 3;
  for (int k0 = 0; k0 < 512; k0 += 64){
    __syncthreads();
    *(uint4*)&Al[row][ch*16] = *(const uint4*)(A + (size_t)(r0+row)*512 + k0 + ch*16);
    #pragma unroll
    for (int j = 0; j < 5; ++j)
      *(uint4*)&Bl[j][row][ch*16] =
        *(const uint4*)(Bbase + ((size_t)j << 18) + (size_t)row*512 + k0 + ch*16);
    __syncthreads();
    v4i bf[5];
    #pragma unroll
    for (int j = 0; j < 5; ++j) bf[j] = *(const v4i*)&Bl[j][wv*16 + (l&15)][(l>>4)*16];
    #pragma unroll
    for (int rf = 0; rf < 4; ++rf){
      v4i af = *(const v4i*)&Al[rf*16 + (l&15)][(l>>4)*16];
      #pragma unroll
      for (int j = 0; j < 5; ++j)
        acc[rf][j] = __builtin_amdgcn_mfma_i32_16x16x64_i8(af, bf[j], acc[rf][j], 0, 0, 0);
    }
  }
  int col = m0 + wv*16 + (l&15);
  #pragma unroll
  for (int rf = 0; rf < 4; ++rf)
    #pragma unroll
    for (int i = 0; i < 4; ++i){
      int r = r0 + rf*16 + ((l>>4)<<2) + i;
      double d = (double)acc[rf][4][i];
      d = d*256.0 + (double)acc[rf][3][i];
      d = d*256.0 + (double)acc[rf][2][i];
      d = d*256.0 + (double)acc[rf][1][i];
      d = d*256.0 + (double)acc[rf][0][i];
      C[(size_t)r*ldc + col] = (float)(d * 0x1p-39);
    }
}

// ---------------- i8 attention: y = ((QK^T) masked) V * 1/8 — exact integers ----------------
__global__ __launch_bounds__(256) void attn_i8(const unsigned char* __restrict__ Q,
                                               const unsigned char* __restrict__ K,
                                               const unsigned char* __restrict__ V,
                                               const int* __restrict__ mask,
                                               float* __restrict__ Y){
  __shared__ signed char Ql[64][80];
  __shared__ signed char Kl[64][80];
  __shared__ signed char Vt[64][80];   // transposed: [d][s]
  __shared__ signed char Pl[64][80];
  int tid = threadIdx.x, l = tid & 63, wv = tid >> 6;
  int bh = blockIdx.y, b = bh >> 3, h = bh & 7;
  int t0 = blockIdx.x << 6;
  int row = tid >> 2, ch = tid & 3;
  *(uint4*)&Ql[row][ch*16] = *(const uint4*)(Q + ((size_t)(bh*512 + t0 + row))*64 + ch*16);
  __syncthreads();
  v4i qfrag = *(const v4i*)&Ql[wv*16 + (l&15)][(l>>4)*16];
  v4i zero = {0,0,0,0};
  v4i yac[4] = {zero, zero, zero, zero};
  for (int s0 = 0; s0 < 512; s0 += 64){
    __syncthreads();
    {
      *(uint4*)&Kl[row][ch*16] = *(const uint4*)(K + ((size_t)(bh*512 + s0 + row))*64 + ch*16);
      uint4 vvv = *(const uint4*)(V + (size_t)(s0+row)*RR + b*NN + h*DD + ch*16);
      const unsigned char* pb = (const unsigned char*)&vvv;
      #pragma unroll
      for (int j = 0; j < 16; ++j) Vt[ch*16 + j][row] = pb[j];
    }
    __syncthreads();
    #pragma unroll
    for (int sf = 0; sf < 4; ++sf){
      v4i kf = *(const v4i*)&Kl[sf*16 + (l&15)][(l>>4)*16];
      v4i p = __builtin_amdgcn_mfma_i32_16x16x64_i8(qfrag, kf, zero, 0, 0, 0);
      int col = sf*16 + (l&15);
      int mk = mask[b*512 + s0 + col];
      #pragma unroll
      for (int i = 0; i < 4; ++i)
        Pl[wv*16 + ((l>>4)<<2) + i][col] = mk ? (signed char)p[i] : (signed char)0;
    }
    // wave-local P reuse (each wave reads only its own 16 P-rows; in-wave ds ordering)
    v4i pf = *(const v4i*)&Pl[wv*16 + (l&15)][(l>>4)*16];
    #pragma unroll
    for (int df = 0; df < 4; ++df){
      v4i vf = *(const v4i*)&Vt[df*16 + (l&15)][(l>>4)*16];
      yac[df] = __builtin_amdgcn_mfma_i32_16x16x64_i8(pf, vf, yac[df], 0, 0, 0);
    }
  }
  #pragma unroll
  for (int df = 0; df < 4; ++df)
    #pragma unroll
    for (int i = 0; i < 4; ++i)
      Y[((size_t)(bh*512 + t0 + wv*16 + ((l>>4)<<2) + i))*64 + df*16 + (l&15)] =
        (float)yac[df][i] * 0.125f;
}

// ---------------- LIF scans (bit-identical arithmetic to round-2; u8 spike I/O) ----------------
__global__ __launch_bounds__(64) void lif_u8(const float* __restrict__ in,
                                             unsigned char* __restrict__ out){
  int r = blockIdx.x * 64 + threadIdx.x;
  float v = 0.0f;
  for (int t0 = 0; t0 < TT; t0 += LIF_CH){
    float xv[LIF_CH];
    #pragma unroll
    for (int i = 0; i < LIF_CH; ++i) xv[i] = in[(size_t)(t0+i)*RR + r];
    #pragma unroll
    for (int i = 0; i < LIF_CH; ++i){
      v = v * 0.5f + xv[i];
      bool sp = (v >= 1.0f);
      out[(size_t)(t0+i)*RR + r] = sp ? 1 : 0;
      v = sp ? 0.0f : v;
    }
  }
}

__global__ __launch_bounds__(64) void lif2_u8(const float* __restrict__ cq,
                                              const float* __restrict__ ck,
                                              unsigned char* __restrict__ oq,
                                              unsigned char* __restrict__ ok){
  int r = blockIdx.x * 64 + threadIdx.x;   // 0..16383
  int sel = r >> 13, rr = r & 8191;
  const float* in = sel ? ck : cq;
  unsigned char* out = sel ? ok : oq;
  float v = 0.0f;
  for (int t0 = 0; t0 < TT; t0 += LIF_CH){
    float xv[LIF_CH];
    #pragma unroll
    for (int i = 0; i < LIF_CH; ++i) xv[i] = in[(size_t)(t0+i)*RR + rr];
    #pragma unroll
    for (int i = 0; i < LIF_CH; ++i){
      v = v * 0.5f + xv[i];
      bool sp = (v >= 1.0f);
      out[(size_t)(t0+i)*RR + rr] = sp ? 1 : 0;
      v = sp ? 0.0f : v;
    }
  }
}

__global__ __launch_bounds__(64) void lif_bn3_u8(const float* __restrict__ in,   // (T*B,1536)
                                                 const float* __restrict__ qbn,
                                                 const float* __restrict__ kbn,
                                                 const float* __restrict__ vbn,
                                                 unsigned char* __restrict__ oq,
                                                 unsigned char* __restrict__ ok,
                                                 unsigned char* __restrict__ ov){
  int r = blockIdx.x * 64 + threadIdx.x;   // 0..24575
  int mat = r >> 13;
  int rb  = r & 8191;
  int b = rb >> 9, n = rb & 511;
  const float* bnp = (mat == 0) ? qbn : (mat == 1) ? kbn : vbn;
  unsigned char* o = ((mat == 0) ? oq : (mat == 1) ? ok : ov) + b*NN + n;
  double g  = bnp[n];
  double be = bnp[NN + n];
  double m  = bnp[2*NN + n];
  double va = bnp[3*NN + n];
  double sc = g / sqrt(va + 1e-5);
  const float* src = in + (size_t)b*1536 + mat*512 + n;
  float v = 0.0f;
  for (int t0 = 0; t0 < TT; t0 += LIF_CH){
    float xv[LIF_CH];
    #pragma unroll
    for (int i = 0; i < LIF_CH; ++i) xv[i] = src[(size_t)(t0+i)*24576];
    #pragma unroll
    for (int i = 0; i < LIF_CH; ++i){
      float y = (float)(((double)xv[i] - m) * sc + be);
      v = v * 0.5f + y;
      bool sp = (v >= 1.0f);
      o[(size_t)(t0+i)*RR] = sp ? 1 : 0;
      v = sp ? 0.0f : v;
    }
  }
}

__global__ __launch_bounds__(64) void lif_bn_f32(const float* __restrict__ in,
                                                 const float* __restrict__ bnp,
                                                 float* __restrict__ out){
  int r = blockIdx.x * 64 + threadIdx.x;
  int n = r & (NN - 1);
  double g  = bnp[n];
  double be = bnp[NN + n];
  double m  = bnp[2*NN + n];
  double va = bnp[3*NN + n];
  double sc = g / sqrt(va + 1e-5);
  float v = 0.0f;
  for (int t0 = 0; t0 < TT; t0 += LIF_CH){
    float xv[LIF_CH];
    #pragma unroll
    for (int i = 0; i < LIF_CH; ++i) xv[i] = in[(size_t)(t0+i)*RR + r];
    #pragma unroll
    for (int i = 0; i < LIF_CH; ++i){
      float y = (float)(((double)xv[i] - m) * sc + be);
      v = v * 0.5f + y;
      bool sp = (v >= 1.0f);
      out[(size_t)(t0+i)*RR + r] = sp ? 1.0f : 0.0f;
      v = sp ? 0.0f : v;
    }
  }
}

__global__ __launch_bounds__(64) void lif_attn_u8(const float* __restrict__ in,  // (B,H,T,D)
                                                  unsigned char* __restrict__ out){ // (T,B,N)
  int r = blockIdx.x * 64 + threadIdx.x;   // (bh,d)
  int bh = r >> 6, d = r & 63;
  int b = bh >> 3, h = bh & 7;
  const float* src = in + (size_t)bh * TT * DD + d;
  unsigned char* dst = out + b * NN + h * DD + d;
  float v = 0.0f;
  for (int t0 = 0; t0 < TT; t0 += LIF_CH){
    float xv[LIF_CH];
    #pragma unroll
    for (int i = 0; i < LIF_CH; ++i) xv[i] = src[(size_t)(t0+i)*DD];
    #pragma unroll
    for (int i = 0; i < LIF_CH; ++i){
      v = v * 0.5f + xv[i];
      bool sp = (v >= 1.0f);
      dst[(size_t)(t0+i)*RR] = sp ? 1 : 0;
      v = sp ? 0.0f : v;
    }
  }
}

// ---------------- rotary (q,k fused): u8 spikes -> fp32 (B,H,T,D), fp64 table math ----------------
__global__ __launch_bounds__(256) void rotary2_u8(const unsigned char* __restrict__ q1,
                                                  const unsigned char* __restrict__ k1,
                                                  const double* __restrict__ tab,
                                                  float* __restrict__ oq,
                                                  float* __restrict__ ok){
  int pid = blockIdx.x * 256 + threadIdx.x;      // 2 * 2^21
  int sel = pid >> 21;
  int id  = pid & ((1 << 21) - 1);
  int p  = id & 31;
  int t  = (id >> 5) & (TT - 1);
  int bh = id >> 14;
  int b  = bh >> 3, h = bh & 7;
  const unsigned char* s = (sel ? k1 : q1) + ((size_t)(t*BB + b))*NN + h*DD + p*2;
  double x0 = (double)s[0], x1 = (double)s[1];
  double cs = tab[(t*32 + p)*2], sn = tab[(t*32 + p)*2 + 1];
  float2 o;
  o.x = (float)(x0*cs - x1*sn);
  o.y = (float)(x1*cs + x0*sn);
  *(float2*)((sel ? ok : oq) + ((size_t)(bh*TT + t))*DD + p*2) = o;
}

extern "C" void kernel_launch(void* const* d_in, const int* in_sizes, int n_in,
                              void* d_out, int out_size, void* d_ws, size_t ws_size,
                              hipStream_t stream){
  (void)in_sizes; (void)n_in; (void)out_size; (void)ws_size;
  const float* x    = (const float*)d_in[0];
  const int*   mask = (const int*)d_in[1];
  const float* lng  = (const float*)d_in[2];
  const float* lnb  = (const float*)d_in[3];
  const float* wq   = (const float*)d_in[4];
  const float* qbn  = (const float*)d_in[5];
  const float* wk   = (const float*)d_in[6];
  const float* kbn  = (const float*)d_in[7];
  const float* wv   = (const float*)d_in[8];
  const float* vbn  = (const float*)d_in[9];
  const float* wp   = (const float*)d_in[10];
  const float* pbn  = (const float*)d_in[11];
  float* out = (float*)d_out;

  const size_t MB = 1ull << 20;
  char* ws = (char*)d_ws;
  float* C3          = (float*)(ws);                 // 48MB: gemm3 out / LN out / rotary outs / attn y
  unsigned char* XS  = (unsigned char*)(ws + 48*MB); // head spikes (T,B,N)
  unsigned char* T1Q = (unsigned char*)(ws + 52*MB); // q1 spikes, later attn-lif spikes
  unsigned char* T1K = (unsigned char*)(ws + 56*MB); // k1 spikes
  unsigned char* Qb  = (unsigned char*)(ws + 60*MB); // Q spikes (B,H,T,D)
  unsigned char* Kb  = (unsigned char*)(ws + 64*MB); // K spikes (B,H,T,D)
  unsigned char* Vb  = (unsigned char*)(ws + 68*MB); // V spikes (T,B,N)
  signed char*   SLI = (signed char*)(ws + 72*MB);   // 4 mats x 5 slices x 256KB
  double*        TAB = (double*)(ws + 77*MB);        // 256KB rope table
  float* CQ = C3;                                    // rotary q out (16MB)
  float* CK = C3 + 4*MB;                             // rotary k out (bytes offset 16MB)
  float* Y  = C3 + 8*MB;                             // attn y (bytes offset 32MB)

  rope_table<<<64, 256, 0, stream>>>(TAB);
  slice_kernel<<<4096, 256, 0, stream>>>(wq, wk, wv, wp, SLI);

  ln_kernel<<<2048, 256, 0, stream>>>(x, lng, lnb, C3);
  lif_u8<<<128, 64, 0, stream>>>(C3, XS);

  gemm_i8<<<dim3(128, 24), 256, 0, stream>>>(XS, SLI, C3, 1536);      // q|k|v fused
  lif_bn3_u8<<<384, 64, 0, stream>>>(C3, qbn, kbn, vbn, T1Q, T1K, Vb);
  rotary2_u8<<<16384, 256, 0, stream>>>(T1Q, T1K, TAB, CQ, CK);
  lif2_u8<<<256, 64, 0, stream>>>(CQ, CK, Qb, Kb);                    // flat (512,8192) scans

  attn_i8<<<dim3(8, 128), 256, 0, stream>>>(Qb, Kb, Vb, mask, Y);
  lif_attn_u8<<<128, 64, 0, stream>>>(Y, T1Q);

  gemm_i8<<<dim3(128, 8), 256, 0, stream>>>(T1Q, SLI + 15*262144, C3, 512);
  lif_bn_f32<<<128, 64, 0, stream>>>(C3, pbn, out);
}

// Round 9
// 325.468 us; speedup vs baseline: 2.7002x; 1.0663x over previous
//
#include <hip/hip_runtime.h>
#include <math.h>

#define TT 512
#define BB 16
#define NN 512
#define HH 8
#define DD 64
#define RR 8192      // BB*NN

typedef int v4i __attribute__((ext_vector_type(4)));

__device__ __forceinline__ double wave_sum_d(double v){
  #pragma unroll
  for (int off = 32; off > 0; off >>= 1) v += __shfl_xor(v, off, 64);
  return v;
}

// Packed fragment layout for u8 matrices X[R][K]:
//   (r,k) -> ((r>>4)*(K/16) + (k>>4))*256 + (r&15)*16 + (k&15)
// => every 16x64 MFMA fragment is a contiguous lane-ordered 1KB block.

// ---------------- LayerNorm over feature dim (fp64 math, fp32 out) ----------------
__global__ __launch_bounds__(256) void ln_kernel(const float* __restrict__ x,
                                                 const float* __restrict__ lng,
                                                 const float* __restrict__ lnb,
                                                 float* __restrict__ out){
  int row  = (blockIdx.x * 256 + threadIdx.x) >> 6;
  int lane = threadIdx.x & 63;
  const float* src = x + (size_t)row * NN;
  int n0 = lane * 4;
  float4 v0 = *(const float4*)(src + n0);
  float4 v1 = *(const float4*)(src + 256 + n0);
  double e[8] = {v0.x, v0.y, v0.z, v0.w, v1.x, v1.y, v1.z, v1.w};
  double s = 0.0;
  #pragma unroll
  for (int i = 0; i < 8; ++i) s += e[i];
  s = wave_sum_d(s);
  double mean = s * (1.0/512.0);
  double ss = 0.0;
  #pragma unroll
  for (int i = 0; i < 8; ++i){ double d = e[i] - mean; ss += d * d; }
  ss = wave_sum_d(ss);
  double inv = 1.0 / sqrt(ss * (1.0/512.0) + 1e-5);
  float4 g0 = *(const float4*)(lng + n0);
  float4 g1 = *(const float4*)(lng + 256 + n0);
  float4 b0 = *(const float4*)(lnb + n0);
  float4 b1 = *(const float4*)(lnb + 256 + n0);
  double gg[8] = {g0.x, g0.y, g0.z, g0.w, g1.x, g1.y, g1.z, g1.w};
  double bb[8] = {b0.x, b0.y, b0.z, b0.w, b1.x, b1.y, b1.z, b1.w};
  float o[8];
  #pragma unroll
  for (int i = 0; i < 8; ++i)
    o[i] = (float)((e[i] - mean) * inv * gg[i] + bb[i]);
  float* dst = out + (size_t)row * NN;
  *(float4*)(dst + n0)       = make_float4(o[0], o[1], o[2], o[3]);
  *(float4*)(dst + 256 + n0) = make_float4(o[4], o[5], o[6], o[7]);
}

// ---------------- weight slicing: W fp32 -> 5 signed-i8 planes (PACKED), scale 2^-39 ----------------
__global__ __launch_bounds__(256) void slice_pack(const float* __restrict__ w0,
                                                  const float* __restrict__ w1,
                                                  const float* __restrict__ w2,
                                                  const float* __restrict__ w3,
                                                  signed char* __restrict__ out){
  int id = blockIdx.x * 256 + threadIdx.x;      // 4*262144
  int wi = id >> 18, e = id & 262143;
  const float* w = wi==0 ? w0 : wi==1 ? w1 : wi==2 ? w2 : w3;
  double q = (double)w[e] * 0x1p39;
  long long Qv = (long long)rint(q);
  int m = e >> 9, k = e & 511;
  size_t poff = (size_t)(m >> 4) * 8192 + (size_t)(k >> 4) * 256 + (m & 15) * 16 + (k & 15);
  signed char* dst = out + ((size_t)(wi*5) << 18) + poff;
  #pragma unroll
  for (int j = 0; j < 4; ++j){
    signed char bch = (signed char)(Qv & 255);
    dst[(size_t)j << 18] = bch;
    Qv = (Qv - bch) >> 8;
  }
  dst[(size_t)4 << 18] = (signed char)Qv;
}

// ---------------- rotary table of f32 outcomes: {cs, sn, cs-sn, cs+sn} (fp64 internally) ----------------
__global__ __launch_bounds__(256) void rope_tabf(float4* __restrict__ tab){
  int id = blockIdx.x * 256 + threadIdx.x;      // 16384 = 512 t x 32 p
  int t = id >> 5, p = id & 31;
  double inv = pow(10000.0, -(double)p / 32.0);
  double f = (double)t * inv;
  double sn, cs; sincos(f, &sn, &cs);
  tab[id] = make_float4((float)cs, (float)sn, (float)(cs - sn), (float)(cs + sn));
}

// ---------------- i8 slice-GEMM v2: packed A & B, 128x64 tile, linear LDS ----------------
__global__ __launch_bounds__(256) void gemm_i8(const unsigned char* __restrict__ A,
                                               const signed char* __restrict__ SL,
                                               float* __restrict__ C, int ldc){
  __shared__ __align__(16) unsigned char Ls[28 * 1024];   // A: 8KB | B: 20KB
  int tid = threadIdx.x, l = tid & 63, wv = tid >> 6;
  int r0 = blockIdx.x << 7;         // 128 rows
  int m0 = blockIdx.y << 6;         // 64 cols
  int mat = m0 >> 9, mm0 = m0 & 511;
  const unsigned char* Abase = A + (size_t)(r0 >> 4) * 8192 + l * 16;
  const signed char*  Bbase = SL + ((size_t)(mat*5) << 18) + (size_t)(mm0 >> 4) * 8192 + l * 16;
  v4i zero = {0,0,0,0};
  v4i acc[8][5];
  #pragma unroll
  for (int rf = 0; rf < 8; ++rf)
    #pragma unroll
    for (int j = 0; j < 5; ++j) acc[rf][j] = zero;
  for (int k0 = 0; k0 < 512; k0 += 64){
    int kc = (k0 >> 4) << 8;
    __syncthreads();
    #pragma unroll
    for (int c = 0; c < 7; ++c){
      int ch = wv + (c << 2);       // wave wv stages chunks wv, wv+4, ..., wv+24
      uint4 dat;
      if (ch < 8){
        dat = *(const uint4*)(Abase + (size_t)ch * 8192 + kc);
      } else {
        int bc = ch - 8; int mg = bc / 5, jj = bc % 5;
        dat = *(const uint4*)(Bbase + ((size_t)jj << 18) + (size_t)mg * 8192 + kc);
      }
      *(uint4*)(Ls + ch * 1024 + l * 16) = dat;
    }
    __syncthreads();
    v4i bf[5];
    #pragma unroll
    for (int j = 0; j < 5; ++j)
      bf[j] = *(const v4i*)(Ls + 8192 + (wv * 5 + j) * 1024 + l * 16);
    #pragma unroll
    for (int rf = 0; rf < 8; ++rf){
      v4i af = *(const v4i*)(Ls + rf * 1024 + l * 16);
      #pragma unroll
      for (int j = 0; j < 5; ++j)
        acc[rf][j] = __builtin_amdgcn_mfma_i32_16x16x64_i8(af, bf[j], acc[rf][j], 0, 0, 0);
    }
  }
  int col = m0 + wv * 16 + (l & 15);
  #pragma unroll
  for (int rf = 0; rf < 8; ++rf)
    #pragma unroll
    for (int i = 0; i < 4; ++i){
      int r = r0 + rf * 16 + ((l >> 4) << 2) + i;
      double d = (double)acc[rf][4][i];
      d = d*256.0 + (double)acc[rf][3][i];
      d = d*256.0 + (double)acc[rf][2][i];
      d = d*256.0 + (double)acc[rf][1][i];
      d = d*256.0 + (double)acc[rf][0][i];
      C[(size_t)r * ldc + col] = (float)(d * 0x1p-39);
    }
}

// ---------------- i8 attention v2: packed Q/K/V direct-to-reg, barrier-free ----------------
__global__ __launch_bounds__(256) void attn_i8(const unsigned char* __restrict__ Q,
                                               const unsigned char* __restrict__ K,
                                               const unsigned char* __restrict__ V,
                                               const int* __restrict__ mask,
                                               float* __restrict__ Y){
  __shared__ __align__(16) signed char Pl[4096];   // 1KB per wave, wave-private
  int tid = threadIdx.x, l = tid & 63, wv = tid >> 6;
  int bh = blockIdx.y, b = bh >> 3;
  int t0 = blockIdx.x << 6;
  const unsigned char* Qb = Q + (size_t)bh * 32768;
  const unsigned char* Kb = K + (size_t)bh * 32768;
  const unsigned char* Vb = V + (size_t)bh * 32768;
  v4i qf = *(const v4i*)(Qb + ((size_t)((t0 >> 4) + wv)) * 1024 + l * 16);
  v4i zero = {0,0,0,0};
  v4i yac[4] = {zero, zero, zero, zero};
  signed char* Pw = Pl + wv * 1024;
  for (int s0 = 0; s0 < 512; s0 += 64){
    #pragma unroll
    for (int sf = 0; sf < 4; ++sf){
      v4i kf = *(const v4i*)(Kb + ((size_t)((s0 >> 4) + sf)) * 1024 + l * 16);
      v4i p = __builtin_amdgcn_mfma_i32_16x16x64_i8(qf, kf, zero, 0, 0, 0);
      int mk = mask[b * 512 + s0 + sf * 16 + (l & 15)];
      #pragma unroll
      for (int i = 0; i < 4; ++i)
        Pw[sf * 256 + (l >> 4) * 64 + i * 16 + (l & 15)] = mk ? (signed char)p[i] : (signed char)0;
    }
    v4i pf = *(const v4i*)(Pw + l * 16);         // in-wave lgkmcnt ordering
    #pragma unroll
    for (int df = 0; df < 4; ++df){
      v4i vf = *(const v4i*)(Vb + (size_t)df * 8192 + ((s0 >> 4)) * 256 + l * 16);
      yac[df] = __builtin_amdgcn_mfma_i32_16x16x64_i8(pf, vf, yac[df], 0, 0, 0);
    }
  }
  #pragma unroll
  for (int df = 0; df < 4; ++df)
    #pragma unroll
    for (int i = 0; i < 4; ++i)
      Y[((size_t)(bh * 512 + t0 + wv * 16 + ((l >> 4) << 2) + i)) * 64 + df * 16 + (l & 15)] =
        (float)yac[df][i] * 0.125f;
}

// ---------------- LIF scans: bit-identical arithmetic, double-buffered prefetch ----------------
// head LIF: (T,B,N) fp32 -> packed spikes (GEMM-A pack: row (t*16+b) -> byte t*8192 + base)
__global__ __launch_bounds__(64) void lif_u8(const float* __restrict__ in,
                                             unsigned char* __restrict__ out){
  int r = blockIdx.x * 64 + threadIdx.x;
  int b = r >> 9, n = r & 511;
  unsigned char* op = out + (size_t)(n >> 4) * 256 + b * 16 + (n & 15);
  float xa[32], xb[32];
  float v = 0.0f;
  #pragma unroll
  for (int i = 0; i < 32; ++i) xa[i] = in[(size_t)i * RR + r];
  for (int t0 = 0; t0 < TT; t0 += 64){
    #pragma unroll
    for (int i = 0; i < 32; ++i) xb[i] = in[(size_t)(t0 + 32 + i) * RR + r];
    #pragma unroll
    for (int i = 0; i < 32; ++i){
      v = v * 0.5f + xa[i];
      bool sp = (v >= 1.0f);
      op[(size_t)(t0 + i) * 8192] = sp ? 1 : 0;
      v = sp ? 0.0f : v;
    }
    if (t0 + 64 < TT){
      #pragma unroll
      for (int i = 0; i < 32; ++i) xa[i] = in[(size_t)(t0 + 64 + i) * RR + r];
    }
    #pragma unroll
    for (int i = 0; i < 32; ++i){
      v = v * 0.5f + xb[i];
      bool sp = (v >= 1.0f);
      op[(size_t)(t0 + 32 + i) * 8192] = sp ? 1 : 0;
      v = sp ? 0.0f : v;
    }
  }
}

// BN + LIF x3 (q,k flat spikes; v packed [d][s] for attention B-operand)
__global__ __launch_bounds__(64) void lif_bn3_u8(const float* __restrict__ in,   // (T*B,1536)
                                                 const float* __restrict__ qbn,
                                                 const float* __restrict__ kbn,
                                                 const float* __restrict__ vbn,
                                                 unsigned char* __restrict__ oq,
                                                 unsigned char* __restrict__ ok,
                                                 unsigned char* __restrict__ ov){
  int r = blockIdx.x * 64 + threadIdx.x;   // 0..24575
  int mat = r >> 13;
  int rb  = r & 8191;
  int b = rb >> 9, n = rb & 511;
  const float* bnp = (mat == 0) ? qbn : (mat == 1) ? kbn : vbn;
  double g  = bnp[n];
  double be = bnp[NN + n];
  double m  = bnp[2*NN + n];
  double va = bnp[3*NN + n];
  double sc = g / sqrt(va + 1e-5);
  const float* src = in + (size_t)b * 1536 + mat * 512 + n;
  bool packed = (mat == 2);
  int h = n >> 6, d = n & 63;
  unsigned char* obase;
  if (packed) obase = ov + (size_t)(b * 8 + h) * 32768 + (size_t)(d >> 4) * 8192 + (d & 15) * 16;
  else        obase = ((mat == 0) ? oq : ok) + (size_t)b * NN + n;
  float xa[32], xb[32];
  float v = 0.0f;
  #pragma unroll
  for (int i = 0; i < 32; ++i) xa[i] = src[(size_t)i * 24576];
  for (int t0 = 0; t0 < TT; t0 += 64){
    #pragma unroll
    for (int i = 0; i < 32; ++i) xb[i] = src[(size_t)(t0 + 32 + i) * 24576];
    #pragma unroll
    for (int i = 0; i < 32; ++i){
      int t = t0 + i;
      float y = (float)(((double)xa[i] - m) * sc + be);
      v = v * 0.5f + y;
      bool sp = (v >= 1.0f);
      size_t off = packed ? ((size_t)(t >> 4) * 256 + (t & 15)) : ((size_t)t * RR);
      obase[off] = sp ? 1 : 0;
      v = sp ? 0.0f : v;
    }
    if (t0 + 64 < TT){
      #pragma unroll
      for (int i = 0; i < 32; ++i) xa[i] = src[(size_t)(t0 + 64 + i) * 24576];
    }
    #pragma unroll
    for (int i = 0; i < 32; ++i){
      int t = t0 + 32 + i;
      float y = (float)(((double)xb[i] - m) * sc + be);
      v = v * 0.5f + y;
      bool sp = (v >= 1.0f);
      size_t off = packed ? ((size_t)(t >> 4) * 256 + (t & 15)) : ((size_t)t * RR);
      obase[off] = sp ? 1 : 0;
      v = sp ? 0.0f : v;
    }
  }
}

// fused rotary + post-rotary LIF (flat (512,8192) scan over (B,H,T,D) view), packed Q/K out
__global__ __launch_bounds__(64) void lif_rot2(const unsigned char* __restrict__ q1,
                                               const unsigned char* __restrict__ k1,
                                               const float4* __restrict__ tab,
                                               unsigned char* __restrict__ oq,
                                               unsigned char* __restrict__ ok){
  int j = blockIdx.x * 64 + threadIdx.x;   // 0..16383
  int sel = j >> 13, jr = j & 8191;
  int t7 = jr >> 6, d = jr & 63, p = d >> 1, odd = d & 1;
  const unsigned char* in = sel ? k1 : q1;
  unsigned char* outp = sel ? ok : oq;
  float4 tv0 = tab[((0 << 7 | t7) << 5) + p];
  float4 tv1 = tab[((1 << 7 | t7) << 5) + p];
  float4 tv2 = tab[((2 << 7 | t7) << 5) + p];
  float4 tv3 = tab[((3 << 7 | t7) << 5) + p];
  int xa[32], xb[32];
  float v = 0.0f;
  #pragma unroll
  for (int i = 0; i < 32; ++i){
    int s = i; int bhh = s >> 2, t = ((s & 3) << 7) | t7;
    xa[i] = in[((size_t)t * 16 + (bhh >> 3)) * 512 + (bhh & 7) * 64 + d];
  }
  for (int s0 = 0; s0 < TT; s0 += 64){
    #pragma unroll
    for (int i = 0; i < 32; ++i){
      int s = s0 + 32 + i; int bhh = s >> 2, t = ((s & 3) << 7) | t7;
      xb[i] = in[((size_t)t * 16 + (bhh >> 3)) * 512 + (bhh & 7) * 64 + d];
    }
    #pragma unroll
    for (int i = 0; i < 32; ++i){
      int s = s0 + i; int c = s & 3; int bhh = s >> 2;
      int xs = xa[i];
      int xp = __shfl_xor(xs, 1, 64);
      float4 tt = (c == 0) ? tv0 : (c == 1) ? tv1 : (c == 2) ? tv2 : tv3;
      float val = xs ? (xp ? (odd ? tt.w : tt.z) : tt.x)
                     : (xp ? (odd ? tt.y : -tt.y) : 0.0f);
      v = v * 0.5f + val;
      bool sp = (v >= 1.0f);
      int t = (c << 7) | t7;
      outp[(size_t)bhh * 32768 + ((size_t)(t >> 4) * 4 + (d >> 4)) * 256 + (t & 15) * 16 + (d & 15)] = sp ? 1 : 0;
      v = sp ? 0.0f : v;
    }
    if (s0 + 64 < TT){
      #pragma unroll
      for (int i = 0; i < 32; ++i){
        int s = s0 + 64 + i; int bhh = s >> 2, t = ((s & 3) << 7) | t7;
        xa[i] = in[((size_t)t * 16 + (bhh >> 3)) * 512 + (bhh & 7) * 64 + d];
      }
    }
    #pragma unroll
    for (int i = 0; i < 32; ++i){
      int s = s0 + 32 + i; int c = s & 3; int bhh = s >> 2;
      int xs = xb[i];
      int xp = __shfl_xor(xs, 1, 64);
      float4 tt = (c == 0) ? tv0 : (c == 1) ? tv1 : (c == 2) ? tv2 : tv3;
      float val = xs ? (xp ? (odd ? tt.w : tt.z) : tt.x)
                     : (xp ? (odd ? tt.y : -tt.y) : 0.0f);
      v = v * 0.5f + val;
      bool sp = (v >= 1.0f);
      int t = (c << 7) | t7;
      outp[(size_t)bhh * 32768 + ((size_t)(t >> 4) * 4 + (d >> 4)) * 256 + (t & 15) * 16 + (d & 15)] = sp ? 1 : 0;
      v = sp ? 0.0f : v;
    }
  }
}

// attn LIF: (B,H,T,D) fp32 -> packed spikes for proj GEMM
__global__ __launch_bounds__(64) void lif_attn_u8(const float* __restrict__ in,
                                                  unsigned char* __restrict__ out){
  int r = blockIdx.x * 64 + threadIdx.x;   // (bh,d)
  int bh = r >> 6, d = r & 63;
  int b = bh >> 3, h = bh & 7;
  int n = h * 64 + d;
  const float* src = in + (size_t)bh * TT * DD + d;
  unsigned char* op = out + (size_t)(n >> 4) * 256 + b * 16 + (n & 15);
  float xa[32], xb[32];
  float v = 0.0f;
  #pragma unroll
  for (int i = 0; i < 32; ++i) xa[i] = src[(size_t)i * DD];
  for (int t0 = 0; t0 < TT; t0 += 64){
    #pragma unroll
    for (int i = 0; i < 32; ++i) xb[i] = src[(size_t)(t0 + 32 + i) * DD];
    #pragma unroll
    for (int i = 0; i < 32; ++i){
      int t = t0 + i;
      v = v * 0.5f + xa[i];
      bool sp = (v >= 1.0f);
      op[(size_t)t * 8192] = sp ? 1 : 0;
      v = sp ? 0.0f : v;
    }
    if (t0 + 64 < TT){
      #pragma unroll
      for (int i = 0; i < 32; ++i) xa[i] = src[(size_t)(t0 + 64 + i) * DD];
    }
    #pragma unroll
    for (int i = 0; i < 32; ++i){
      int t = t0 + 32 + i;
      v = v * 0.5f + xb[i];
      bool sp = (v >= 1.0f);
      op[(size_t)t * 8192] = sp ? 1 : 0;
      v = sp ? 0.0f : v;
    }
  }
}

// final BN + LIF -> fp32 (T,B,N) output
__global__ __launch_bounds__(64) void lif_bn_f32(const float* __restrict__ in,
                                                 const float* __restrict__ bnp,
                                                 float* __restrict__ out){
  int r = blockIdx.x * 64 + threadIdx.x;
  int n = r & (NN - 1);
  double g  = bnp[n];
  double be = bnp[NN + n];
  double m  = bnp[2*NN + n];
  double va = bnp[3*NN + n];
  double sc = g / sqrt(va + 1e-5);
  float xa[32], xb[32];
  float v = 0.0f;
  #pragma unroll
  for (int i = 0; i < 32; ++i) xa[i] = in[(size_t)i * RR + r];
  for (int t0 = 0; t0 < TT; t0 += 64){
    #pragma unroll
    for (int i = 0; i < 32; ++i) xb[i] = in[(size_t)(t0 + 32 + i) * RR + r];
    #pragma unroll
    for (int i = 0; i < 32; ++i){
      float y = (float)(((double)xa[i] - m) * sc + be);
      v = v * 0.5f + y;
      bool sp = (v >= 1.0f);
      out[(size_t)(t0 + i) * RR + r] = sp ? 1.0f : 0.0f;
      v = sp ? 0.0f : v;
    }
    if (t0 + 64 < TT){
      #pragma unroll
      for (int i = 0; i < 32; ++i) xa[i] = in[(size_t)(t0 + 64 + i) * RR + r];
    }
    #pragma unroll
    for (int i = 0; i < 32; ++i){
      float y = (float)(((double)xb[i] - m) * sc + be);
      v = v * 0.5f + y;
      bool sp = (v >= 1.0f);
      out[(size_t)(t0 + 32 + i) * RR + r] = sp ? 1.0f : 0.0f;
      v = sp ? 0.0f : v;
    }
  }
}

extern "C" void kernel_launch(void* const* d_in, const int* in_sizes, int n_in,
                              void* d_out, int out_size, void* d_ws, size_t ws_size,
                              hipStream_t stream){
  (void)in_sizes; (void)n_in; (void)out_size; (void)ws_size;
  const float* x    = (const float*)d_in[0];
  const int*   mask = (const int*)d_in[1];
  const float* lng  = (const float*)d_in[2];
  const float* lnb  = (const float*)d_in[3];
  const float* wq   = (const float*)d_in[4];
  const float* qbn  = (const float*)d_in[5];
  const float* wk   = (const float*)d_in[6];
  const float* kbn  = (const float*)d_in[7];
  const float* wv   = (const float*)d_in[8];
  const float* vbn  = (const float*)d_in[9];
  const float* wp   = (const float*)d_in[10];
  const float* pbn  = (const float*)d_in[11];
  float* out = (float*)d_out;

  const size_t MB = 1ull << 20;
  char* ws = (char*)d_ws;
  float* C3          = (float*)(ws);                 // 0..48MB: LN out / gemm3 out / Y / (proj out at +16MB)
  unsigned char* XS  = (unsigned char*)(ws + 48*MB); // packed head spikes
  unsigned char* T1Q = (unsigned char*)(ws + 52*MB); // q1 flat spikes; later packed attn spikes
  unsigned char* T1K = (unsigned char*)(ws + 56*MB); // k1 flat spikes
  unsigned char* Qb  = (unsigned char*)(ws + 60*MB); // packed Q spikes (per-bh 32KB)
  unsigned char* Kb  = (unsigned char*)(ws + 64*MB); // packed K spikes
  unsigned char* Vb  = (unsigned char*)(ws + 68*MB); // packed V spikes
  signed char*   SLI = (signed char*)(ws + 72*MB);   // 4 mats x 5 slices x 256KB (packed)
  float4*        TABF= (float4*)(ws + 77*MB);        // 256KB rotary outcome table
  float* Y  = C3;                                    // attn y (B,H,T,D) 16MB
  float* CP = C3 + 4*MB;                             // proj out (bytes +16MB)

  rope_tabf<<<64, 256, 0, stream>>>(TABF);
  slice_pack<<<4096, 256, 0, stream>>>(wq, wk, wv, wp, SLI);

  ln_kernel<<<2048, 256, 0, stream>>>(x, lng, lnb, C3);
  lif_u8<<<128, 64, 0, stream>>>(C3, XS);

  gemm_i8<<<dim3(64, 24), 256, 0, stream>>>(XS, SLI, C3, 1536);        // q|k|v fused
  lif_bn3_u8<<<384, 64, 0, stream>>>(C3, qbn, kbn, vbn, T1Q, T1K, Vb);
  lif_rot2<<<256, 64, 0, stream>>>(T1Q, T1K, TABF, Qb, Kb);            // rotary+LIF fused

  attn_i8<<<dim3(8, 128), 256, 0, stream>>>(Qb, Kb, Vb, mask, Y);
  lif_attn_u8<<<128, 64, 0, stream>>>(Y, T1Q);                         // packed out

  gemm_i8<<<dim3(64, 8), 256, 0, stream>>>(T1Q, SLI + ((size_t)15 << 18), CP, 512);
  lif_bn_f32<<<128, 64, 0, stream>>>(CP, pbn, out);
}